// Round 3
// baseline (341.736 us; speedup 1.0000x reference)
//
#include <hip/hip_runtime.h>

#define DN 128
#define LS 136   // LDS row stride in shorts (272 B = 68 u32 -> 4-bank rotation/row)

typedef short s16x8 __attribute__((ext_vector_type(8)));
typedef float f32x4 __attribute__((ext_vector_type(4)));

__device__ __forceinline__ float bf2f(unsigned short u) {
    union { unsigned int i; float f; } v; v.i = ((unsigned int)u) << 16; return v.f;
}
__device__ __forceinline__ unsigned short f2bf(float f) {
    union { float f; unsigned int i; } v; v.f = f;
    unsigned int r = v.i + 0x7fffu + ((v.i >> 16) & 1u);
    return (unsigned short)(r >> 16);
}
__device__ __forceinline__ float lo16(unsigned int u) { return bf2f((unsigned short)(u & 0xffffu)); }
__device__ __forceinline__ float hi16(unsigned int u) { return bf2f((unsigned short)(u >> 16)); }
__device__ __forceinline__ unsigned int pack2(float x, float y) {
    return (unsigned int)f2bf(x) | ((unsigned int)f2bf(y) << 16);
}
__device__ __forceinline__ float ldx(const void* p, size_t i, int f32) {
    return f32 ? ((const float*)p)[i] : bf2f(((const unsigned short*)p)[i]);
}

__global__ void k_diag(unsigned short* out, int cnt, float val) {
    unsigned short v = f2bf(val);
    for (int i = blockIdx.x * blockDim.x + threadIdx.x; i < cnt; i += gridDim.x * blockDim.x)
        out[i] = v;
}

// ---- dtype probes, parallel (flags pre-zeroed) ----
__global__ void k_probe(const void* x, const void* w, const int* e, int* flags) {
    int g = blockIdx.x * 256 + threadIdx.x;          // 0 .. 32767
    const unsigned short* xu = (const unsigned short*)x;
    int hitx = 0, hitw = 0, hite = 0;
    for (int i = g; i < 65536; i += 32768)
        if ((xu[i] & 0x7F80u) == 0x7F80u) hitx = 1;
    const unsigned short* wu = (const unsigned short*)w;
    if (g < 16384 && (wu[g] & 0x7F80u) == 0x7F80u) hitw = 1;
    if (g < 1000 && e[2 * g + 1] != 0) hite = 1;
    if (hitx) atomicOr(&flags[0], 1);
    if (hitw) atomicOr(&flags[2], 1);
    if (hite) atomicOr(&flags[1], 1);
}

// ---- cast x -> bf16-packed u32 ----
__global__ void k_cast(const void* x, const int* xflagp, unsigned int* xb, int cnt) {
    int i = blockIdx.x * blockDim.x + threadIdx.x;
    if (i >= cnt) return;
    if (*xflagp) {
        float2 v = *(const float2*)((const float*)x + 2 * (size_t)i);
        xb[i] = pack2(v.x, v.y);
    } else {
        xb[i] = ((const unsigned int*)x)[i];
    }
}

// ======== CSR build: 2-level MSD bucket partition (R13/R14) ========
// ids < 65536 -> edge packs to u32 (dst<<16)|src; bucket = dst>>8.
// R14: pack+hist fused (one edge-list pass); level-1 scatter writes runs
// directly (no LDS reorder); level-2 scan is single-wave shfl (2 barriers).

// pack edges -> u32 keys + per-bucket totals (LDS hist, 256 atomics/block)
__global__ __launch_bounds__(1024) void k_packhist(const int* e, const int* flags,
        unsigned int* packed, int* cnt, int E, int n) {
    __shared__ int hist[256];
    int t = threadIdx.x;
    int b0 = blockIdx.x * 4096;
    if (t < 256) hist[t] = 0;
    __syncthreads();
    int is64 = (flags[1] == 0);
#pragma unroll
    for (int k = 0; k < 4; ++k) {
        int i = b0 + t + k * 1024;
        if (i < E) {
            int d = is64 ? e[2 * (E + i)] : e[E + i];
            int s = is64 ? e[2 * i] : e[i];
            if ((unsigned)s >= (unsigned)n) s = 0;
            unsigned int key = ((unsigned)d < (unsigned)n)
                             ? (((unsigned)d << 16) | (unsigned)s)
                             : 0xFFFF0000u;
            packed[i] = key;
            atomicAdd(&hist[key >> 24], 1);
        }
    }
    __syncthreads();
    if (t < 256 && hist[t]) atomicAdd(&cnt[t], hist[t]);
}

// exclusive scan of 256 bucket counts; init run cursors; rowp[n] = valid count
__global__ void k_s256(const int* cnt, int* base, int* cursor, int* rowp, int n) {
    __shared__ int buf[256];
    int t = threadIdx.x;
    int v = cnt[t];
    buf[t] = v;
    __syncthreads();
    for (int off = 1; off < 256; off <<= 1) {
        int add = (t >= off) ? buf[t - off] : 0;
        __syncthreads();
        buf[t] += add;
        __syncthreads();
    }
    base[t] = buf[t] - v;       // exclusive
    cursor[t] = buf[t] - v;
    if (t == 255) base[256] = buf[255];
    if (t == 195) rowp[n] = buf[195];   // valid edges (buckets 0..195)
}

// level-1 scatter: per-(block,bucket) run reservation, direct run writes
__global__ __launch_bounds__(1024) void k_p1scat(const unsigned int* in, int* gcur,
                                                 unsigned int* out, int E) {
    __shared__ int hist[256], lcur[256], gbase[256];
    int t = threadIdx.x;
    int b0 = blockIdx.x * 4096;
    int nb = E - b0; if (nb > 4096) nb = 4096;
    if (t < 256) hist[t] = 0;
    __syncthreads();
    unsigned int v[4];
#pragma unroll
    for (int k = 0; k < 4; ++k) {
        int i = t + k * 1024;
        v[k] = (i < nb) ? in[b0 + i] : 0u;
        if (i < nb) atomicAdd(&hist[v[k] >> 24], 1);
    }
    __syncthreads();
    if (t < 256) {
        lcur[t] = 0;
        if (hist[t]) gbase[t] = atomicAdd(&gcur[t], hist[t]);
    }
    __syncthreads();
#pragma unroll
    for (int k = 0; k < 4; ++k) {
        int i = t + k * 1024;
        if (i < nb) {
            unsigned int d = v[k] >> 24;
            int p = atomicAdd(&lcur[d], 1);
            out[gbase[d] + p] = v[k];
        }
    }
}

// level-2: per-bucket local CSR inside a private window; single-wave scan
__global__ __launch_bounds__(1024) void k_p2(const unsigned int* in, const int* base,
                                             int* rowp, int* col, int n) {
    __shared__ int hist[256], cur[256];
    int t = threadIdx.x;
    int b = blockIdx.x;                  // 0..195
    int lo = base[b], hi = base[b + 1];
    if (t < 256) hist[t] = 0;
    __syncthreads();
    for (int i = lo + t; i < hi; i += 1024)
        atomicAdd(&hist[(in[i] >> 16) & 0xFFu], 1);
    __syncthreads();
    if (t < 64) {
        int h0 = hist[4 * t], h1 = hist[4 * t + 1], h2 = hist[4 * t + 2], h3 = hist[4 * t + 3];
        int tot = h0 + h1 + h2 + h3;
        int pre = tot;
#pragma unroll
        for (int off = 1; off < 64; off <<= 1) {
            int u = __shfl_up(pre, off, 64);
            if (t >= off) pre += u;
        }
        int e0 = pre - tot;              // exclusive start of bucket 4t
        int e1 = e0 + h0, e2 = e1 + h1, e3 = e2 + h2;
        cur[4 * t] = e0; cur[4 * t + 1] = e1; cur[4 * t + 2] = e2; cur[4 * t + 3] = e3;
        int d0 = b * 256 + 4 * t;
        if (d0 < n)     rowp[d0]     = lo + e0;
        if (d0 + 1 < n) rowp[d0 + 1] = lo + e1;
        if (d0 + 2 < n) rowp[d0 + 2] = lo + e2;
        if (d0 + 3 < n) rowp[d0 + 3] = lo + e3;
    }
    __syncthreads();
    for (int i = lo + t; i < hi; i += 1024) {
        unsigned int v = in[i];
        int p = atomicAdd(&cur[(v >> 16) & 0xFFu], 1);
        col[lo + p] = (int)(v & 0xFFFFu);
    }
}

// ---- fused gather+GEMM: hout = relu([mean_nbr(hin) | hin] @ [Wl|Wr]^T + b) ----
// block 256 = 4 waves; tile 64 rows x 128 cols. Wave wv gathers its OWN 16
// MFMA A-rows directly into sA (lane L produces cols {2L,2L+1} = sAu[r*68+L]),
// so M never materializes (saves 25.6 MB round-trip + a staging pass + 2
// launches vs separate k_gather/k_gemm). Wl staging is issued before the
// gather so its loads fly underneath. hout MUST differ from hin (other
// blocks gather-read arbitrary hin rows).
__global__ __launch_bounds__(256) void k_gg(
        const int* rowp, const int* col, const unsigned int* hin,
        const void* Wl, const void* Wr, const void* bias, const int* wflagp,
        unsigned int* hout, int n) {
    __shared__ unsigned short sA[64 * LS];    // 17 KB
    __shared__ unsigned short sB[128 * LS];   // 35 KB
    unsigned int* sAu = (unsigned int*)sA;
    unsigned int* sBu = (unsigned int*)sB;
    const int t = threadIdx.x;
    const int wf32 = *wflagp;
    const int i0 = blockIdx.x * 64;
    const int lane = t & 63, wv = t >> 6, ln15 = lane & 15, quad = lane >> 4;
    const int L = lane;

    // stage B = Wl first (independent of gather; loads overlap it)
    if (wf32) {
        const float* wp = (const float*)Wl;
#pragma unroll
        for (int i = 0; i < 32; ++i) {
            int idx = t + i * 256, r = idx >> 6, kk = idx & 63;
            float2 f = *(const float2*)(wp + (size_t)r * DN + 2 * kk);
            sBu[r * 68 + kk] = pack2(f.x, f.y);
        }
    } else {
        const unsigned int* wp = (const unsigned int*)Wl;
#pragma unroll
        for (int i = 0; i < 32; ++i) {
            int idx = t + i * 256, r = idx >> 6, kk = idx & 63;
            sBu[r * 68 + kk] = wp[(size_t)r * 64 + kk];
        }
    }

    // gather: wave wv aggregates rows i0+wv*16 .. +15 into sA (8-deep MLP)
    for (int rr = 0; rr < 16; ++rr) {
        int r = wv * 16 + rr;
        int row = i0 + r;
        float s0 = 0.f, s1 = 0.f;
        int deg = 0;
        if (row < n) {
            int rb = rowp[row], re = rowp[row + 1];
            deg = re - rb;
            for (int base = rb; base < re; base += 64) {
                int cnt = re - base; if (cnt > 64) cnt = 64;
                int myc = (L < cnt) ? col[base + L] : 0;
                int j = 0;
                for (; j + 8 <= cnt; j += 8) {
                    int a0 = __shfl(myc, j + 0, 64);
                    int a1 = __shfl(myc, j + 1, 64);
                    int a2 = __shfl(myc, j + 2, 64);
                    int a3 = __shfl(myc, j + 3, 64);
                    int a4 = __shfl(myc, j + 4, 64);
                    int a5 = __shfl(myc, j + 5, 64);
                    int a6 = __shfl(myc, j + 6, 64);
                    int a7 = __shfl(myc, j + 7, 64);
                    unsigned int u0 = hin[(size_t)a0 * 64 + L];
                    unsigned int u1 = hin[(size_t)a1 * 64 + L];
                    unsigned int u2 = hin[(size_t)a2 * 64 + L];
                    unsigned int u3 = hin[(size_t)a3 * 64 + L];
                    unsigned int u4 = hin[(size_t)a4 * 64 + L];
                    unsigned int u5 = hin[(size_t)a5 * 64 + L];
                    unsigned int u6 = hin[(size_t)a6 * 64 + L];
                    unsigned int u7 = hin[(size_t)a7 * 64 + L];
                    s0 += lo16(u0); s1 += hi16(u0);
                    s0 += lo16(u1); s1 += hi16(u1);
                    s0 += lo16(u2); s1 += hi16(u2);
                    s0 += lo16(u3); s1 += hi16(u3);
                    s0 += lo16(u4); s1 += hi16(u4);
                    s0 += lo16(u5); s1 += hi16(u5);
                    s0 += lo16(u6); s1 += hi16(u6);
                    s0 += lo16(u7); s1 += hi16(u7);
                }
                for (; j + 4 <= cnt; j += 4) {
                    int a0 = __shfl(myc, j + 0, 64);
                    int a1 = __shfl(myc, j + 1, 64);
                    int a2 = __shfl(myc, j + 2, 64);
                    int a3 = __shfl(myc, j + 3, 64);
                    unsigned int u0 = hin[(size_t)a0 * 64 + L];
                    unsigned int u1 = hin[(size_t)a1 * 64 + L];
                    unsigned int u2 = hin[(size_t)a2 * 64 + L];
                    unsigned int u3 = hin[(size_t)a3 * 64 + L];
                    s0 += lo16(u0); s1 += hi16(u0);
                    s0 += lo16(u1); s1 += hi16(u1);
                    s0 += lo16(u2); s1 += hi16(u2);
                    s0 += lo16(u3); s1 += hi16(u3);
                }
                for (; j < cnt; ++j) {
                    int s = __shfl(myc, j, 64);
                    unsigned int u = hin[(size_t)s * 64 + L];
                    s0 += lo16(u); s1 += hi16(u);
                }
            }
        }
        int d = (deg < 1) ? 1 : deg;
        float inv = 1.0f / (float)d;
        sAu[r * 68 + L] = pack2(s0 * inv, s1 * inv);
    }
    __syncthreads();

    f32x4 acc[8];
#pragma unroll
    for (int i = 0; i < 8; ++i) { f32x4 z = {0.f, 0.f, 0.f, 0.f}; acc[i] = z; }

    const int mrow = wv * 16;
    // phase 0: A = gathered means (already in sA), B = Wl
#pragma unroll
    for (int ks = 0; ks < 4; ++ks) {
        s16x8 a = *(const s16x8*)&sA[(mrow + ln15) * LS + ks * 32 + quad * 8];
#pragma unroll
        for (int nt = 0; nt < 8; ++nt) {
            s16x8 bfr = *(const s16x8*)&sB[(nt * 16 + ln15) * LS + ks * 32 + quad * 8];
            acc[nt] = __builtin_amdgcn_mfma_f32_16x16x32_bf16(a, bfr, acc[nt], 0, 0, 0);
        }
    }
    __syncthreads();

    // phase 1: A = own hin rows, B = Wr
#pragma unroll
    for (int i = 0; i < 16; ++i) {
        int idx = t + i * 256, r = idx >> 6, c = idx & 63;
        int node = i0 + r;
        sAu[r * 68 + c] = (node < n) ? hin[(size_t)node * 64 + c] : 0u;
    }
    if (wf32) {
        const float* wp = (const float*)Wr;
#pragma unroll
        for (int i = 0; i < 32; ++i) {
            int idx = t + i * 256, r = idx >> 6, kk = idx & 63;
            float2 f = *(const float2*)(wp + (size_t)r * DN + 2 * kk);
            sBu[r * 68 + kk] = pack2(f.x, f.y);
        }
    } else {
        const unsigned int* wp = (const unsigned int*)Wr;
#pragma unroll
        for (int i = 0; i < 32; ++i) {
            int idx = t + i * 256, r = idx >> 6, kk = idx & 63;
            sBu[r * 68 + kk] = wp[(size_t)r * 64 + kk];
        }
    }
    __syncthreads();
#pragma unroll
    for (int ks = 0; ks < 4; ++ks) {
        s16x8 a = *(const s16x8*)&sA[(mrow + ln15) * LS + ks * 32 + quad * 8];
#pragma unroll
        for (int nt = 0; nt < 8; ++nt) {
            s16x8 bfr = *(const s16x8*)&sB[(nt * 16 + ln15) * LS + ks * 32 + quad * 8];
            acc[nt] = __builtin_amdgcn_mfma_f32_16x16x32_bf16(a, bfr, acc[nt], 0, 0, 0);
        }
    }

    // epilogue: bias + relu + bf16 store
    // C/D layout (16x16x32): col = lane&15, row = quad*4 + reg  [learn_hip m89]
#pragma unroll
    for (int nt = 0; nt < 8; ++nt) {
        int colv = nt * 16 + ln15;
        float bs = ldx(bias, colv, wf32);
#pragma unroll
        for (int r = 0; r < 4; ++r) {
            int node = i0 + wv * 16 + quad * 4 + r;
            if (node < n) {
                float v = acc[nt][r] + bs;
                v = (v > 0.f) ? v : 0.f;
                ((unsigned short*)hout)[(size_t)node * DN + colv] = f2bf(v);
            }
        }
    }
}

// ---- LayerNorm + mixed-dtype sentinel (k_mix folded in) ----
__global__ void k_ln(const unsigned int* h2, const void* w, const void* b,
                     void* out, int n, const int* flags) {
    int wave = blockIdx.x * (blockDim.x >> 6) + (threadIdx.x >> 6);
    int lane = threadIdx.x & 63;
    if (wave >= n) return;
    int wf32 = flags[2];
    int outf32 = (flags[0] && flags[2]);
    if (flags[0] != flags[2]) {           // mixed dtypes -> sentinel fill
        ((unsigned int*)out)[(size_t)wave * 64 + lane] = 0x442F442Fu;
        return;
    }
    unsigned int u = h2[(size_t)wave * 64 + lane];
    float a = lo16(u), c = hi16(u);
    float s = a + c;
#pragma unroll
    for (int off = 32; off; off >>= 1) s += __shfl_xor(s, off, 64);
    float mu = s * (1.0f / 128.0f);
    float da = a - mu, dc = c - mu;
    float q = da * da + dc * dc;
#pragma unroll
    for (int off = 32; off; off >>= 1) q += __shfl_xor(q, off, 64);
    float rs = rsqrtf(q * (1.0f / 128.0f) + 1e-5f);
    float o0 = da * rs * ldx(w, 2 * lane, wf32) + ldx(b, 2 * lane, wf32);
    float o1 = dc * rs * ldx(w, 2 * lane + 1, wf32) + ldx(b, 2 * lane + 1, wf32);
    if (outf32) {
        float2 v; v.x = o0; v.y = o1;
        ((float2*)out)[(size_t)wave * 64 + lane] = v;
    } else {
        ((unsigned int*)out)[(size_t)wave * 64 + lane] = pack2(o0, o1);
    }
}

extern "C" void kernel_launch(void* const* d_in, const int* in_sizes, int n_in,
                              void* d_out, int out_size, void* d_ws, size_t ws_size,
                              hipStream_t stream) {
    const int N_EXP = 50000, E_EXP = 800000;

    const size_t sz_flags  = 256;
    const size_t sz_rowp   = (((size_t)(N_EXP + 1) * 4) + 255) & ~(size_t)255;
    const size_t sz_cursor = (((size_t)N_EXP * 4) + 255) & ~(size_t)255;
    const size_t sz_col    = (((size_t)E_EXP * 4) + 255) & ~(size_t)255;
    const size_t sz_M      = (size_t)N_EXP * 64 * 4;
    const size_t sz_h      = (size_t)N_EXP * DN * 2;
    const size_t need = sz_flags + sz_rowp + sz_cursor + sz_col + sz_M + sz_h;

    float diag = 0.f;
    if (in_sizes[0] != N_EXP * DN) diag += 1000.f;
    if (in_sizes[1] != 2 * E_EXP)  diag += 2000.f;
    if (n_in != 10)                diag += 4000.f;
    if (out_size != N_EXP * DN)    diag += 8000.f;
    if (ws_size < need)            diag += 16000.f;
    if (diag != 0.f) {
        k_diag<<<1024, 256, 0, stream>>>((unsigned short*)d_out, N_EXP * DN, diag);
        return;
    }

    const void* x   = d_in[0];
    const int*  ei  = (const int*)d_in[1];
    const void* W1l = d_in[2];
    const void* b1l = d_in[3];
    const void* W1r = d_in[4];
    const void* W2l = d_in[5];
    const void* b2l = d_in[6];
    const void* W2r = d_in[7];
    const void* lnw = d_in[8];
    const void* lnb = d_in[9];

    const int n = N_EXP, E = E_EXP;

    char* ws = (char*)d_ws;
    int* flags  = (int*)ws;
    int* rowp   = (int*)(ws + sz_flags);
    int* small  = (int*)(ws + sz_flags + sz_rowp);          // old cursor region
    int* col    = (int*)(ws + sz_flags + sz_rowp + sz_cursor);
    unsigned int* M  = (unsigned int*)(ws + sz_flags + sz_rowp + sz_cursor + sz_col);
    unsigned int* h1 = (unsigned int*)(ws + sz_flags + sz_rowp + sz_cursor + sz_col + sz_M);

    // cnt aliases rowp[0..255]: consumed by k_s256 before k_p2 writes rowp.
    // One memset covers flags (256 B) + cnt (1 KB), contiguous at ws+0.
    int* cnt   = (int*)(ws + sz_flags);    // == rowp
    int* bbase = small;                    // [257] scanned bucket bases
    int* bcur  = small + 260;              // [256] run-reservation cursors
    // packed0 borrows col's slot (dead after p1scat; p2 overwrites col).
    // packed1 borrows M's slot (dead before k_gg uses it as h2).
    unsigned int* packed0 = (unsigned int*)col;
    unsigned int* packed1 = (unsigned int*)M;
    unsigned int* h2 = (unsigned int*)M;   // layer-1 output ping-pong buffer

    hipMemsetAsync(ws, 0, 1280, stream);   // flags + cnt

    k_probe<<<128, 256, 0, stream>>>(x, W1l, ei, flags);

    // CSR build
    int P1B = (E + 4095) / 4096;   // 196 (== #buckets for n=50000)
    k_packhist<<<P1B, 1024, 0, stream>>>(ei, flags, packed0, cnt, E, n);
    k_s256<<<1, 256, 0, stream>>>(cnt, bbase, bcur, rowp, n);
    k_p1scat<<<P1B, 1024, 0, stream>>>(packed0, bcur, packed1, E);
    k_p2<<<P1B, 1024, 0, stream>>>(packed1, bbase, rowp, col, n);

    // cast x -> bf16 packed into h1
    int cc = n * 64;
    k_cast<<<(cc + 255) / 256, 256, 0, stream>>>(x, &flags[0], h1, cc);

    int mb = (n + 63) / 64;

    // layer 1: h1 -> h2 ; layer 2: h2 -> h1 (gather+gemm fused; no M)
    k_gg<<<mb, 256, 0, stream>>>(rowp, col, h1, W1l, W1r, b1l, &flags[2], h2, n);
    k_gg<<<mb, 256, 0, stream>>>(rowp, col, h2, W2l, W2r, b2l, &flags[2], h1, n);
    // layernorm (+ mixed-dtype sentinel)
    k_ln<<<(n + 3) / 4, 256, 0, stream>>>(h1, lnw, lnb, d_out, n, flags);
}

// Round 4
// 255.938 us; speedup vs baseline: 1.3352x; 1.3352x over previous
//
#include <hip/hip_runtime.h>

#define DN 128
#define LS 136   // LDS row stride in shorts (272 B = 68 u32 -> 4-bank rotation/row)

typedef short s16x8 __attribute__((ext_vector_type(8)));
typedef float f32x4 __attribute__((ext_vector_type(4)));

__device__ __forceinline__ float bf2f(unsigned short u) {
    union { unsigned int i; float f; } v; v.i = ((unsigned int)u) << 16; return v.f;
}
__device__ __forceinline__ unsigned short f2bf(float f) {
    union { float f; unsigned int i; } v; v.f = f;
    unsigned int r = v.i + 0x7fffu + ((v.i >> 16) & 1u);
    return (unsigned short)(r >> 16);
}
__device__ __forceinline__ float lo16(unsigned int u) { return bf2f((unsigned short)(u & 0xffffu)); }
__device__ __forceinline__ float hi16(unsigned int u) { return bf2f((unsigned short)(u >> 16)); }
__device__ __forceinline__ unsigned int pack2(float x, float y) {
    return (unsigned int)f2bf(x) | ((unsigned int)f2bf(y) << 16);
}
__device__ __forceinline__ float ldx(const void* p, size_t i, int f32) {
    return f32 ? ((const float*)p)[i] : bf2f(((const unsigned short*)p)[i]);
}

__global__ void k_diag(unsigned short* out, int cnt, float val) {
    unsigned short v = f2bf(val);
    for (int i = blockIdx.x * blockDim.x + threadIdx.x; i < cnt; i += gridDim.x * blockDim.x)
        out[i] = v;
}

// ---- dtype probes, parallel (flags pre-zeroed) ----
__global__ void k_probe(const void* x, const void* w, const int* e, int* flags) {
    int g = blockIdx.x * 256 + threadIdx.x;          // 0 .. 32767
    const unsigned short* xu = (const unsigned short*)x;
    int hitx = 0, hitw = 0, hite = 0;
    for (int i = g; i < 65536; i += 32768)
        if ((xu[i] & 0x7F80u) == 0x7F80u) hitx = 1;
    const unsigned short* wu = (const unsigned short*)w;
    if (g < 16384 && (wu[g] & 0x7F80u) == 0x7F80u) hitw = 1;
    if (g < 1000 && e[2 * g + 1] != 0) hite = 1;
    if (hitx) atomicOr(&flags[0], 1);
    if (hitw) atomicOr(&flags[2], 1);
    if (hite) atomicOr(&flags[1], 1);
}

// ---- cast x -> bf16-packed u32 ----
__global__ void k_cast(const void* x, const int* xflagp, unsigned int* xb, int cnt) {
    int i = blockIdx.x * blockDim.x + threadIdx.x;
    if (i >= cnt) return;
    if (*xflagp) {
        float2 v = *(const float2*)((const float*)x + 2 * (size_t)i);
        xb[i] = pack2(v.x, v.y);
    } else {
        xb[i] = ((const unsigned int*)x)[i];
    }
}

// ======== CSR build: 2-level MSD bucket partition (R13/R14) ========
// ids < 65536 -> edge packs to u32 (dst<<16)|src; bucket = dst>>8.

// pack edges -> u32 keys + per-bucket totals (LDS hist, 256 atomics/block)
__global__ __launch_bounds__(1024) void k_packhist(const int* e, const int* flags,
        unsigned int* packed, int* cnt, int E, int n) {
    __shared__ int hist[256];
    int t = threadIdx.x;
    int b0 = blockIdx.x * 4096;
    if (t < 256) hist[t] = 0;
    __syncthreads();
    int is64 = (flags[1] == 0);
#pragma unroll
    for (int k = 0; k < 4; ++k) {
        int i = b0 + t + k * 1024;
        if (i < E) {
            int d = is64 ? e[2 * (E + i)] : e[E + i];
            int s = is64 ? e[2 * i] : e[i];
            if ((unsigned)s >= (unsigned)n) s = 0;
            unsigned int key = ((unsigned)d < (unsigned)n)
                             ? (((unsigned)d << 16) | (unsigned)s)
                             : 0xFFFF0000u;
            packed[i] = key;
            atomicAdd(&hist[key >> 24], 1);
        }
    }
    __syncthreads();
    if (t < 256 && hist[t]) atomicAdd(&cnt[t], hist[t]);
}

// exclusive scan of 256 bucket counts; init run cursors; rowp[n] = valid count
__global__ void k_s256(const int* cnt, int* base, int* cursor, int* rowp, int n) {
    __shared__ int buf[256];
    int t = threadIdx.x;
    int v = cnt[t];
    buf[t] = v;
    __syncthreads();
    for (int off = 1; off < 256; off <<= 1) {
        int add = (t >= off) ? buf[t - off] : 0;
        __syncthreads();
        buf[t] += add;
        __syncthreads();
    }
    base[t] = buf[t] - v;       // exclusive
    cursor[t] = buf[t] - v;
    if (t == 255) base[256] = buf[255];
    if (t == 195) rowp[n] = buf[195];   // valid edges (buckets 0..195)
}

// level-1 scatter: per-(block,bucket) run reservation, direct run writes
__global__ __launch_bounds__(1024) void k_p1scat(const unsigned int* in, int* gcur,
                                                 unsigned int* out, int E) {
    __shared__ int hist[256], lcur[256], gbase[256];
    int t = threadIdx.x;
    int b0 = blockIdx.x * 4096;
    int nb = E - b0; if (nb > 4096) nb = 4096;
    if (t < 256) hist[t] = 0;
    __syncthreads();
    unsigned int v[4];
#pragma unroll
    for (int k = 0; k < 4; ++k) {
        int i = t + k * 1024;
        v[k] = (i < nb) ? in[b0 + i] : 0u;
        if (i < nb) atomicAdd(&hist[v[k] >> 24], 1);
    }
    __syncthreads();
    if (t < 256) {
        lcur[t] = 0;
        if (hist[t]) gbase[t] = atomicAdd(&gcur[t], hist[t]);
    }
    __syncthreads();
#pragma unroll
    for (int k = 0; k < 4; ++k) {
        int i = t + k * 1024;
        if (i < nb) {
            unsigned int d = v[k] >> 24;
            int p = atomicAdd(&lcur[d], 1);
            out[gbase[d] + p] = v[k];
        }
    }
}

// level-2: per-bucket local CSR inside a private window; single-wave scan
__global__ __launch_bounds__(1024) void k_p2(const unsigned int* in, const int* base,
                                             int* rowp, int* col, int n) {
    __shared__ int hist[256], cur[256];
    int t = threadIdx.x;
    int b = blockIdx.x;                  // 0..195
    int lo = base[b], hi = base[b + 1];
    if (t < 256) hist[t] = 0;
    __syncthreads();
    for (int i = lo + t; i < hi; i += 1024)
        atomicAdd(&hist[(in[i] >> 16) & 0xFFu], 1);
    __syncthreads();
    if (t < 64) {
        int h0 = hist[4 * t], h1 = hist[4 * t + 1], h2 = hist[4 * t + 2], h3 = hist[4 * t + 3];
        int tot = h0 + h1 + h2 + h3;
        int pre = tot;
#pragma unroll
        for (int off = 1; off < 64; off <<= 1) {
            int u = __shfl_up(pre, off, 64);
            if (t >= off) pre += u;
        }
        int e0 = pre - tot;              // exclusive start of bucket 4t
        int e1 = e0 + h0, e2 = e1 + h1, e3 = e2 + h2;
        cur[4 * t] = e0; cur[4 * t + 1] = e1; cur[4 * t + 2] = e2; cur[4 * t + 3] = e3;
        int d0 = b * 256 + 4 * t;
        if (d0 < n)     rowp[d0]     = lo + e0;
        if (d0 + 1 < n) rowp[d0 + 1] = lo + e1;
        if (d0 + 2 < n) rowp[d0 + 2] = lo + e2;
        if (d0 + 3 < n) rowp[d0 + 3] = lo + e3;
    }
    __syncthreads();
    for (int i = lo + t; i < hi; i += 1024) {
        unsigned int v = in[i];
        int p = atomicAdd(&cur[(v >> 16) & 0xFFu], 1);
        col[lo + p] = (int)(v & 0xFFFFu);
    }
}

// ---- CSR mean gather: 8-deep software-pipelined neighbor loads ----
// one wave per row (12500 blocks x 4 waves -> high occupancy; R15 lesson:
// NEVER serialize multiple rows per wave, latency-hiding needs wave count).
__global__ void k_gather(const int* rowp, const int* col, const unsigned int* hp,
                         unsigned int* M, int n) {
    int row = blockIdx.x * 4 + (threadIdx.x >> 6);
    if (row >= n) return;
    const int L = threadIdx.x & 63;
    int b = rowp[row], e = rowp[row + 1];
    float s0 = 0.f, s1 = 0.f;
    for (int base = b; base < e; base += 64) {
        int cnt = e - base; if (cnt > 64) cnt = 64;
        int myc = (L < cnt) ? col[base + L] : 0;
        int j = 0;
        for (; j + 8 <= cnt; j += 8) {
            int a0 = __shfl(myc, j + 0, 64);
            int a1 = __shfl(myc, j + 1, 64);
            int a2 = __shfl(myc, j + 2, 64);
            int a3 = __shfl(myc, j + 3, 64);
            int a4 = __shfl(myc, j + 4, 64);
            int a5 = __shfl(myc, j + 5, 64);
            int a6 = __shfl(myc, j + 6, 64);
            int a7 = __shfl(myc, j + 7, 64);
            unsigned int u0 = hp[(size_t)a0 * 64 + L];
            unsigned int u1 = hp[(size_t)a1 * 64 + L];
            unsigned int u2 = hp[(size_t)a2 * 64 + L];
            unsigned int u3 = hp[(size_t)a3 * 64 + L];
            unsigned int u4 = hp[(size_t)a4 * 64 + L];
            unsigned int u5 = hp[(size_t)a5 * 64 + L];
            unsigned int u6 = hp[(size_t)a6 * 64 + L];
            unsigned int u7 = hp[(size_t)a7 * 64 + L];
            s0 += lo16(u0); s1 += hi16(u0);
            s0 += lo16(u1); s1 += hi16(u1);
            s0 += lo16(u2); s1 += hi16(u2);
            s0 += lo16(u3); s1 += hi16(u3);
            s0 += lo16(u4); s1 += hi16(u4);
            s0 += lo16(u5); s1 += hi16(u5);
            s0 += lo16(u6); s1 += hi16(u6);
            s0 += lo16(u7); s1 += hi16(u7);
        }
        for (; j + 4 <= cnt; j += 4) {
            int a0 = __shfl(myc, j + 0, 64);
            int a1 = __shfl(myc, j + 1, 64);
            int a2 = __shfl(myc, j + 2, 64);
            int a3 = __shfl(myc, j + 3, 64);
            unsigned int u0 = hp[(size_t)a0 * 64 + L];
            unsigned int u1 = hp[(size_t)a1 * 64 + L];
            unsigned int u2 = hp[(size_t)a2 * 64 + L];
            unsigned int u3 = hp[(size_t)a3 * 64 + L];
            s0 += lo16(u0); s1 += hi16(u0);
            s0 += lo16(u1); s1 += hi16(u1);
            s0 += lo16(u2); s1 += hi16(u2);
            s0 += lo16(u3); s1 += hi16(u3);
        }
        for (; j < cnt; ++j) {
            int s = __shfl(myc, j, 64);
            unsigned int u = hp[(size_t)s * 64 + L];
            s0 += lo16(u); s1 += hi16(u);
        }
    }
    int d = e - b; if (d < 1) d = 1;
    float inv = 1.0f / (float)d;
    M[(size_t)row * 64 + L] = pack2(s0 * inv, s1 * inv);
}

// ---- MFMA GEMM: relu([M | h] @ [Wl|Wr]^T + bias), optional fused LayerNorm ----
// block 256 = 4 waves; tile 64 rows x 128 cols; two K=128 phases (Wl then Wr).
// In-place safe (block reads only its own rows; M separate).
// do_ln: each wave holds its 16 output rows ENTIRELY in-register (row = quad*4+r,
// cols = nt*16+ln15), so LN mean/var = 8 reg adds + shfl_xor {1,2,4,8} (stays
// within the quad's 16-lane group). LN on pre-rounding f32 (more accurate than
// the old bf16-reread k_ln). Mixed-dtype sentinel folded in here too.
__global__ __launch_bounds__(256) void k_gemm(
        const unsigned int* M, const unsigned int* hin,
        const void* Wl, const void* Wr, const void* bias, const int* flags,
        void* hout, int n, int do_ln, const void* lnw, const void* lnb) {
    __shared__ unsigned short sA[64 * LS];    // 17 KB
    __shared__ unsigned short sB[128 * LS];   // 35 KB
    unsigned int* sAu = (unsigned int*)sA;
    unsigned int* sBu = (unsigned int*)sB;
    const int t = threadIdx.x;
    const int wf32 = flags[2];
    const int i0 = blockIdx.x * 64;
    const int lane = t & 63, wv = t >> 6, ln15 = lane & 15, quad = lane >> 4;

    f32x4 acc[8];
#pragma unroll
    for (int i = 0; i < 8; ++i) { f32x4 z = {0.f, 0.f, 0.f, 0.f}; acc[i] = z; }

    for (int phase = 0; phase < 2; ++phase) {
        const unsigned int* A = phase ? hin : M;
#pragma unroll
        for (int i = 0; i < 16; ++i) {
            int idx = t + i * 256, r = idx >> 6, c = idx & 63;
            int node = i0 + r;
            sAu[r * 68 + c] = (node < n) ? A[(size_t)node * 64 + c] : 0u;
        }
        const void* W = phase ? Wr : Wl;
        if (wf32) {
            const float* wp = (const float*)W;
#pragma unroll
            for (int i = 0; i < 32; ++i) {
                int idx = t + i * 256, r = idx >> 6, kk = idx & 63;
                float2 f = *(const float2*)(wp + (size_t)r * DN + 2 * kk);
                sBu[r * 68 + kk] = pack2(f.x, f.y);
            }
        } else {
            const unsigned int* wp = (const unsigned int*)W;
#pragma unroll
            for (int i = 0; i < 32; ++i) {
                int idx = t + i * 256, r = idx >> 6, kk = idx & 63;
                sBu[r * 68 + kk] = wp[(size_t)r * 64 + kk];
            }
        }
        __syncthreads();

        const int mrow = wv * 16;
#pragma unroll
        for (int ks = 0; ks < 4; ++ks) {
            s16x8 a = *(const s16x8*)&sA[(mrow + ln15) * LS + ks * 32 + quad * 8];
#pragma unroll
            for (int nt = 0; nt < 8; ++nt) {
                s16x8 b = *(const s16x8*)&sB[(nt * 16 + ln15) * LS + ks * 32 + quad * 8];
                acc[nt] = __builtin_amdgcn_mfma_f32_16x16x32_bf16(a, b, acc[nt], 0, 0, 0);
            }
        }
        __syncthreads();
    }

    // bias + relu (C/D layout 16x16x32: col = lane&15, row = quad*4 + reg)
#pragma unroll
    for (int nt = 0; nt < 8; ++nt) {
        float bs = ldx(bias, nt * 16 + ln15, wf32);
#pragma unroll
        for (int r = 0; r < 4; ++r) {
            float v = acc[nt][r] + bs;
            acc[nt][r] = (v > 0.f) ? v : 0.f;
        }
    }

    if (!do_ln) {
#pragma unroll
        for (int nt = 0; nt < 8; ++nt) {
            int colv = nt * 16 + ln15;
#pragma unroll
            for (int r = 0; r < 4; ++r) {
                int node = i0 + wv * 16 + quad * 4 + r;
                if (node < n)
                    ((unsigned short*)hout)[(size_t)node * DN + colv] = f2bf(acc[nt][r]);
            }
        }
        return;
    }

    // ---- fused LayerNorm epilogue ----
    const int mix = (flags[0] != flags[2]);
    if (mix) {
#pragma unroll
        for (int nt = 0; nt < 8; ++nt) {
            int colv = nt * 16 + ln15;
#pragma unroll
            for (int r = 0; r < 4; ++r) {
                int node = i0 + wv * 16 + quad * 4 + r;
                if (node < n)
                    ((unsigned short*)hout)[(size_t)node * DN + colv] = 0x442F;
            }
        }
        return;
    }
    const int outf32 = (flags[0] && flags[2]);
    float lw[8], lb[8];
#pragma unroll
    for (int nt = 0; nt < 8; ++nt) {
        lw[nt] = ldx(lnw, nt * 16 + ln15, wf32);
        lb[nt] = ldx(lnb, nt * 16 + ln15, wf32);
    }
#pragma unroll
    for (int r = 0; r < 4; ++r) {
        float s = 0.f;
#pragma unroll
        for (int nt = 0; nt < 8; ++nt) s += acc[nt][r];
#pragma unroll
        for (int off = 1; off < 16; off <<= 1) s += __shfl_xor(s, off, 64);
        float mu = s * (1.0f / 128.0f);
        float q = 0.f;
#pragma unroll
        for (int nt = 0; nt < 8; ++nt) { float d = acc[nt][r] - mu; q += d * d; }
#pragma unroll
        for (int off = 1; off < 16; off <<= 1) q += __shfl_xor(q, off, 64);
        float rs = rsqrtf(q * (1.0f / 128.0f) + 1e-5f);
        int node = i0 + wv * 16 + quad * 4 + r;
        if (node < n) {
#pragma unroll
            for (int nt = 0; nt < 8; ++nt) {
                int colv = nt * 16 + ln15;
                float o = (acc[nt][r] - mu) * rs * lw[nt] + lb[nt];
                if (outf32) ((float*)hout)[(size_t)node * DN + colv] = o;
                else ((unsigned short*)hout)[(size_t)node * DN + colv] = f2bf(o);
            }
        }
    }
}

extern "C" void kernel_launch(void* const* d_in, const int* in_sizes, int n_in,
                              void* d_out, int out_size, void* d_ws, size_t ws_size,
                              hipStream_t stream) {
    const int N_EXP = 50000, E_EXP = 800000;

    const size_t sz_flags  = 256;
    const size_t sz_rowp   = (((size_t)(N_EXP + 1) * 4) + 255) & ~(size_t)255;
    const size_t sz_cursor = (((size_t)N_EXP * 4) + 255) & ~(size_t)255;
    const size_t sz_col    = (((size_t)E_EXP * 4) + 255) & ~(size_t)255;
    const size_t sz_M      = (size_t)N_EXP * 64 * 4;
    const size_t sz_h      = (size_t)N_EXP * DN * 2;
    const size_t need = sz_flags + sz_rowp + sz_cursor + sz_col + sz_M + sz_h;

    float diag = 0.f;
    if (in_sizes[0] != N_EXP * DN) diag += 1000.f;
    if (in_sizes[1] != 2 * E_EXP)  diag += 2000.f;
    if (n_in != 10)                diag += 4000.f;
    if (out_size != N_EXP * DN)    diag += 8000.f;
    if (ws_size < need)            diag += 16000.f;
    if (diag != 0.f) {
        k_diag<<<1024, 256, 0, stream>>>((unsigned short*)d_out, N_EXP * DN, diag);
        return;
    }

    const void* x   = d_in[0];
    const int*  ei  = (const int*)d_in[1];
    const void* W1l = d_in[2];
    const void* b1l = d_in[3];
    const void* W1r = d_in[4];
    const void* W2l = d_in[5];
    const void* b2l = d_in[6];
    const void* W2r = d_in[7];
    const void* lnw = d_in[8];
    const void* lnb = d_in[9];

    const int n = N_EXP, E = E_EXP;

    char* ws = (char*)d_ws;
    int* flags  = (int*)ws;
    int* rowp   = (int*)(ws + sz_flags);
    int* small  = (int*)(ws + sz_flags + sz_rowp);
    int* col    = (int*)(ws + sz_flags + sz_rowp + sz_cursor);
    unsigned int* M  = (unsigned int*)(ws + sz_flags + sz_rowp + sz_cursor + sz_col);
    unsigned int* h1 = (unsigned int*)(ws + sz_flags + sz_rowp + sz_cursor + sz_col + sz_M);

    // cnt aliases rowp[0..255] (consumed by k_s256 before k_p2 writes rowp);
    // one memset covers flags (256 B) + cnt (1 KB) contiguously at ws+0.
    int* cnt   = (int*)(ws + sz_flags);    // == rowp
    int* bbase = small;                    // [257] scanned bucket bases
    int* bcur  = small + 260;              // [256] run-reservation cursors
    // packed0 borrows col's slot; packed1 borrows M's slot (dead before gather).
    unsigned int* packed0 = (unsigned int*)col;
    unsigned int* packed1 = (unsigned int*)M;

    hipMemsetAsync(ws, 0, 1280, stream);   // flags + cnt

    k_probe<<<128, 256, 0, stream>>>(x, W1l, ei, flags);

    // CSR build
    int P1B = (E + 4095) / 4096;   // 196
    k_packhist<<<P1B, 1024, 0, stream>>>(ei, flags, packed0, cnt, E, n);
    k_s256<<<1, 256, 0, stream>>>(cnt, bbase, bcur, rowp, n);
    k_p1scat<<<P1B, 1024, 0, stream>>>(packed0, bcur, packed1, E);
    k_p2<<<P1B, 1024, 0, stream>>>(packed1, bbase, rowp, col, n);

    // cast x -> bf16 packed into h1
    int cc = n * 64;
    k_cast<<<(cc + 255) / 256, 256, 0, stream>>>(x, &flags[0], h1, cc);

    int gb = (n + 3) / 4;
    int mb = (n + 63) / 64;

    // layer 1 (in-place on h1)
    k_gather<<<gb, 256, 0, stream>>>(rowp, col, h1, M, n);
    k_gemm<<<mb, 256, 0, stream>>>(M, h1, W1l, W1r, b1l, flags, h1, n, 0, nullptr, nullptr);
    // layer 2: gemm + fused LayerNorm -> d_out
    k_gather<<<gb, 256, 0, stream>>>(rowp, col, h1, M, n);
    k_gemm<<<mb, 256, 0, stream>>>(M, h1, W2l, W2r, b2l, flags, d_out, n, 1, lnw, lnb);
}